// Round 7
// baseline (417.767 us; speedup 1.0000x reference)
//
#include <hip/hip_runtime.h>
#include <hip/hip_bf16.h>

// CMDNet binary detector: per-batch Gram (MFMA bf16 2-term split, RN rounding)
// + 64 fixed-point iterations with HH held entirely in registers (64 AGPR).
// One wave (64 lanes) per batch element, lane l owns output element m = l.
// R7: cross-lane reduce moved OFF the DS pipe onto VALU permlane swaps
// (v_permlane16/32_swap_b32); acc permuted once (acc[i][k] := acc[i][k^g])
// so per-iter staging needs no cndmasks; th/de hoisted to lane regs.
// Per-iter DS ops: 8 -> 5 (1 ds_write + 4 broadcast ds_read_b128).

typedef __attribute__((ext_vector_type(8))) short bf16x8;
typedef __attribute__((ext_vector_type(4))) float f32x4;
typedef __attribute__((ext_vector_type(2))) float f32x2;
typedef __attribute__((ext_vector_type(4))) int i32x4;
typedef __attribute__((ext_vector_type(2))) int i32x2;

union FragCast { i32x4 i; bf16x8 h; };

#define NTc 64
#define NRc 128

__device__ __forceinline__ float tanh_fast(float x) {
  // tanh(x) = 1 - 2/(exp(2x)+1); exp via v_exp_f32 (exp2). Safe at +/-inf.
  float u = __builtin_amdgcn_exp2f(x * 2.88539008177792681f); // 2*log2(e)
  return 1.0f - 2.0f * __builtin_amdgcn_rcpf(u + 1.0f);
}

__device__ __forceinline__ f32x2 pkfma(f32x2 a, f32x2 b, f32x2 c) {
#if __has_builtin(__builtin_elementwise_fma)
  return __builtin_elementwise_fma(a, b, c);   // lowers to v_pk_fma_f32
#else
  return c + a * b;
#endif
}

__device__ __forceinline__ float rdlane(float v, int lane) {
  return __int_as_float(__builtin_amdgcn_readlane(__float_as_int(v), lane));
}

// Exchange with lane^32 partner on the VALU pipe (no DS traffic).
__device__ __forceinline__ float partner32(float v, int l) {
#if __has_builtin(__builtin_amdgcn_permlane32_swap)
  i32x2 r = __builtin_amdgcn_permlane32_swap(__float_as_int(v),
                                             __float_as_int(v), false, false);
  return __int_as_float((l & 32) ? r.x : r.y);
#else
  return __shfl_xor(v, 32);
#endif
}

// Exchange with lane^16 partner on the VALU pipe.
__device__ __forceinline__ float partner16(float v, int l) {
#if __has_builtin(__builtin_amdgcn_permlane16_swap)
  i32x2 r = __builtin_amdgcn_permlane16_swap(__float_as_int(v),
                                             __float_as_int(v), false, false);
  return __int_as_float((l & 16) ? r.x : r.y);
#else
  // ds_swizzle xor16 fallback (single DS op)
  return __int_as_float(__builtin_amdgcn_ds_swizzle(__float_as_int(v), 0x401F));
#endif
}

// Butterfly reduce of 4 group-partials staged as t_k = p[g^k]:
// A0 = rows(g)+rows(g^2) of col-block g; A1 = same rows of col-block g^1;
// partner16(A1) brings rows(g^1)+rows(g^3) of col-block g. All VALU.
__device__ __forceinline__ float xreduce(float t0, float t1, float t2,
                                         float t3, int l) {
  const float A0 = t0 + partner32(t2, l);
  const float A1 = t1 + partner32(t3, l);
  return A0 + partner16(A1, l);
}

__global__ __launch_bounds__(256, 4)
void cmdnet_bin_kernel(const float* __restrict__ yt, const float* __restrict__ Ht,
                       const float* __restrict__ sig0, const float* __restrict__ alpha,
                       const float* __restrict__ taui, const float* __restrict__ delta,
                       float* __restrict__ out, int B, int n_iter) {
  __shared__ __align__(16) float s_xt[4][64];

  const int tid = threadIdx.x;
  const int w = tid >> 6;        // wave in block
  const int l = tid & 63;        // lane
  const int g = l >> 4;          // lane group 0..3
  const int c = l & 15;          // col within 16-tile
  const int b = blockIdx.x * 4 + w;
  if (b >= B) return;            // wave-uniform (B % 4 == 0)

  const float* __restrict__ Hb = Ht + (size_t)b * (NRc * NTc);
  const float* __restrict__ yb = yt + (size_t)b * NRc;

  // ---- Phase 1: HH = Ht^T Ht via MFMA 16x16x32 bf16, 2-term RN split ----
  // acc[i][q]: lane holds HH[16i + 4g + r][16q + c]  (r = reg 0..3)
  f32x4 acc[4][4];
  #pragma unroll
  for (int i = 0; i < 4; i++)
    #pragma unroll
    for (int j = 0; j < 4; j++) acc[i][j] = (f32x4)0.0f;

  float yhp[4] = {0.0f, 0.0f, 0.0f, 0.0f};  // yH partials per 16-col block

  const int base_l = (g * 8) * NTc + c;

  #pragma unroll
  for (int kk = 0; kk < 4; kk++) {       // K-chunks of 32 rows of Ht[b]
    const float4 ya  = *reinterpret_cast<const float4*>(yb + kk * 32 + g * 8);
    const float4 yb4 = *reinterpret_cast<const float4*>(yb + kk * 32 + g * 8 + 4);
    const float yv[8] = {ya.x, ya.y, ya.z, ya.w, yb4.x, yb4.y, yb4.z, yb4.w};

    FragCast fh[4], fl[4];
    #pragma unroll
    for (int p = 0; p < 4; p++) {        // 4 column-blocks of 16
      #pragma unroll
      for (int jj = 0; jj < 4; jj++) {   // packed word jj holds rows 2jj, 2jj+1
        float v0 = Hb[base_l + kk * 32 * NTc + (2 * jj) * NTc + p * 16];
        float v1 = Hb[base_l + kk * 32 * NTc + (2 * jj + 1) * NTc + p * 16];
        yhp[p] = fmaf(yv[2 * jj], v0, yhp[p]);
        yhp[p] = fmaf(yv[2 * jj + 1], v1, yhp[p]);
        // RN bf16 hi extraction: residual |r| <= 2^-9 |v|; r exact in f32.
        unsigned b0 = __float_as_uint(v0), b1 = __float_as_uint(v1);
        unsigned h0 = (b0 + 0x8000u) & 0xffff0000u;
        unsigned h1 = (b1 + 0x8000u) & 0xffff0000u;
        float r0 = v0 - __uint_as_float(h0);
        float r1 = v1 - __uint_as_float(h1);
        fh[p].i[jj] = (int)((h0 >> 16) | h1);
        fl[p].i[jj] = (int)(((__float_as_uint(r0) + 0x8000u) >> 16) |
                            ((__float_as_uint(r1) + 0x8000u) & 0xffff0000u));
      }
    }
    // D += hi*hi + hi*lo + lo*hi  (dropped lo*lo ~2^-18 relative)
    #pragma unroll
    for (int p = 0; p < 4; p++) {
      #pragma unroll
      for (int q = 0; q < 4; q++) {
        acc[p][q] = __builtin_amdgcn_mfma_f32_16x16x32_bf16(fh[p].h, fh[q].h, acc[p][q], 0, 0, 0);
        acc[p][q] = __builtin_amdgcn_mfma_f32_16x16x32_bf16(fh[p].h, fl[q].h, acc[p][q], 0, 0, 0);
        acc[p][q] = __builtin_amdgcn_mfma_f32_16x16x32_bf16(fl[p].h, fh[q].h, acc[p][q], 0, 0, 0);
      }
    }
  }

  const bool pb0 = (g & 1) != 0;
  const bool pb1 = (g & 2) != 0;

  // One-time permutation: acc[i][k] := acc[i][k ^ g]. After this, the k-th
  // matvec accumulator directly holds the partial destined for staging slot
  // t_k = p[g^k] -- no per-iteration cndmask staging.
  #pragma unroll
  for (int i = 0; i < 4; i++) {
    f32x4 a0 = acc[i][0], a1 = acc[i][1], a2 = acc[i][2], a3 = acc[i][3];
    f32x4 s0 = pb0 ? a1 : a0, s1 = pb0 ? a0 : a1;
    f32x4 s2 = pb0 ? a3 : a2, s3 = pb0 ? a2 : a3;
    acc[i][0] = pb1 ? s2 : s0;
    acc[i][1] = pb1 ? s3 : s1;
    acc[i][2] = pb1 ? s0 : s2;
    acc[i][3] = pb1 ? s1 : s3;
  }

  // yH reduce with the same permuted staging + VALU butterfly.
  float yH_l;
  {
    float s0 = pb0 ? yhp[1] : yhp[0], s1 = pb0 ? yhp[0] : yhp[1];
    float s2 = pb0 ? yhp[3] : yhp[2], s3 = pb0 ? yhp[2] : yhp[3];
    float t0 = pb1 ? s2 : s0, t1 = pb1 ? s3 : s1;
    float t2 = pb1 ? s0 : s2, t3 = pb1 ? s1 : s3;
    yH_l = xreduce(t0, t1, t2, t3, l);
  }

  // ---- Per-lane constants ----
  const float a_l = alpha[l];
  const float c_l = logf(1.0f / a_l - 1.0f);
  const float sg = sig0[b];
  const float sig2 = sg * sg;

  // Hoist per-iteration scalars into lane-indexed VGPRs; in-loop access is
  // a single v_readlane each (no memory, no fabsf/mul on the chain).
  const int li = (l < n_iter) ? l : 0;
  const float v_th = 0.5f * fabsf(taui[li]);   // 0.5*|taui[it]|
  const float v_de = delta[li];

  // ---- Phase 2: n_iter fixed-point iterations ----
  float s = 0.0f;
  float gp = 0.0f;               // sig2 * tanh(s/2); s=0 -> 0
  float last_th = 0.5f;

  auto iter_body = [&](float th_xt, float th_grad, float de) {
    const float xtv = tanh_fast((c_l + s) * th_xt);
    s_xt[w][l] = xtv;            // DS ops in-order per wave; no barrier

    f32x2 t0 = {0.f, 0.f}, t1 = {0.f, 0.f}, t2 = {0.f, 0.f}, t3 = {0.f, 0.f};
    #pragma unroll
    for (int i = 0; i < 4; i++) {
      const f32x4 xv = *reinterpret_cast<const f32x4*>(&s_xt[w][i * 16 + g * 4]);
      const f32x2 xlo = xv.xy, xhi = xv.zw;
      t0 = pkfma(xlo, acc[i][0].xy, t0); t0 = pkfma(xhi, acc[i][0].zw, t0);
      t1 = pkfma(xlo, acc[i][1].xy, t1); t1 = pkfma(xhi, acc[i][1].zw, t1);
      t2 = pkfma(xlo, acc[i][2].xy, t2); t2 = pkfma(xhi, acc[i][2].zw, t2);
      t3 = pkfma(xlo, acc[i][3].xy, t3); t3 = pkfma(xhi, acc[i][3].zw, t3);
    }
    const float xHH = xreduce(t0.x + t0.y, t1.x + t1.y,
                              t2.x + t2.y, t3.x + t3.y, l);
    s = s - de * (gp + th_grad * (1.0f - xtv * xtv) * (xHH - yH_l));
    gp = sig2 * tanh_fast(s * 0.5f);   // prior term for NEXT iteration
  };

  // iteration 0: xt temperature fixed to 1 (0.5 factor only)
  {
    const float th0 = rdlane(v_th, 0);
    iter_body(0.5f, th0, rdlane(v_de, 0));
    last_th = th0;
  }
  for (int it = 1; it < n_iter; it++) {
    const float thg = rdlane(v_th, it);
    const float de = rdlane(v_de, it);
    iter_body(thg, thg, de);
    last_th = thg;
  }

  // ---- Epilogue: ft = [(1-xt)/2, (1+xt)/2], then xt (uses last taui) ----
  const float xtf = tanh_fast((c_l + s) * last_th);
  float2 ft;
  ft.x = 0.5f * (1.0f - xtf);
  ft.y = 0.5f * (1.0f + xtf);
  *reinterpret_cast<float2*>(out + ((size_t)b * NTc + l) * 2) = ft;
  out[(size_t)B * NTc * 2 + (size_t)b * NTc + l] = xtf;
}

extern "C" void kernel_launch(void* const* d_in, const int* in_sizes, int n_in,
                              void* d_out, int out_size, void* d_ws, size_t ws_size,
                              hipStream_t stream) {
  const float* yt    = (const float*)d_in[0];
  const float* Ht    = (const float*)d_in[1];
  const float* sig0  = (const float*)d_in[2];
  const float* alpha = (const float*)d_in[3];
  const float* taui  = (const float*)d_in[4];
  const float* delta = (const float*)d_in[5];
  const int B = in_sizes[2];        // sigmat0 is [B]
  const int n_iter = in_sizes[4];   // taui is [NUM_ITER]

  const int blocks = (B + 3) / 4;   // 4 batches (one wave each) per block
  hipLaunchKernelGGL(cmdnet_bin_kernel, dim3(blocks), dim3(256), 0, stream,
                     yt, Ht, sig0, alpha, taui, delta, (float*)d_out, B, n_iter);
}